// Round 8
// baseline (158.964 us; speedup 1.0000x reference)
//
#include <hip/hip_runtime.h>

// Problem constants (B=2, S=2048, D=1024, H=16, HD=64, W=128 from reference)
#define S_LEN 2048
#define DMODEL 1024
#define NHEAD 16
#define HDIM 64

typedef __bf16 bf16x8 __attribute__((ext_vector_type(8)));
typedef float f32x4 __attribute__((ext_vector_type(4)));

typedef __attribute__((address_space(1))) const void gconst_void;
typedef __attribute__((address_space(3))) void lds_void;

__device__ __forceinline__ unsigned short f2bf(float f) {
    unsigned u = __builtin_bit_cast(unsigned, f);
    u += 0x7fffu + ((u >> 16) & 1u);   // RNE
    return (unsigned short)(u >> 16);
}

// ---------------- fused fp32 -> bf16 convert (x, w1, w2 in one launch) ----------------
#define N4_X  (2 * S_LEN * DMODEL / 4)            // 1048576
#define N4_W1 (3 * DMODEL * DMODEL / 4)           // 786432
#define N4_W2 (DMODEL * DMODEL / 4)               // 262144
__global__ __launch_bounds__(256) void cvt_all(const float* __restrict__ x,
                                               const float* __restrict__ w1,
                                               const float* __restrict__ w2,
                                               unsigned short* __restrict__ xb,
                                               unsigned short* __restrict__ w1b,
                                               unsigned short* __restrict__ w2b) {
    int i = blockIdx.x * 256 + threadIdx.x;
    const float* s;
    unsigned short* d;
    int off;
    if (i < N4_X)            { s = x;  d = xb;  off = i; }
    else if (i < N4_X + N4_W1) { s = w1; d = w1b; off = i - N4_X; }
    else if (i < N4_X + N4_W1 + N4_W2) { s = w2; d = w2b; off = i - N4_X - N4_W1; }
    else return;
    float4 f = ((const float4*)s)[off];
    ushort4 o;
    o.x = f2bf(f.x); o.y = f2bf(f.y); o.z = f2bf(f.z); o.w = f2bf(f.w);
    ((ushort4*)d)[off] = o;
}

// ---------------- GEMM1: qkv projection, 64x64 tile (8 blocks/CU, 32 waves = max) ----
// C[M,N] = A[M,K] * Bt[N,K]^T + bias.  BM=64, BN=64, BK=64, global_load_lds w16.
// n<1024  (q): scaled 0.125 -> qk[m*2048+n]       (bf16)
// n<2048  (k):              -> qk[m*2048+n]       (bf16)
// n>=2048 (v): LDS-transposed -> vT[(b*1024+hd)*2048 + s]  (bf16, coalesced)
// __launch_bounds__(256,8): cap VGPR at 64 so 8 waves/SIMD fit (occupancy is the
// currency in this latency-bound regime: r5->r6 3->6 blk/CU gave -9.7us).
__global__ __launch_bounds__(256, 8) void gemm_qkv(const unsigned short* __restrict__ A,
                                                   const unsigned short* __restrict__ Bt,
                                                   const float* __restrict__ bias,
                                                   unsigned short* __restrict__ qk,
                                                   unsigned short* __restrict__ vT,
                                                   int M, int N, int K) {
    __shared__ unsigned short lds[64 * 64 * 2] __attribute__((aligned(16)));  // 16 KB
    unsigned short* lA = lds;                // 64 x 64
    unsigned short* lB = lds + 64 * 64;      // 64 x 64

    const int tid  = threadIdx.x;
    const int lane = tid & 63;
    const int w    = tid >> 6;
    const int quad = lane >> 4;
    const int l16  = lane & 15;

    const int m0 = blockIdx.x * 64;
    const int n0 = blockIdx.y * 64;

    const int rowi = tid >> 3;                           // 0..31
    const int csw  = ((tid & 7) ^ (rowi & 7)) * 8;       // swizzled source chunk (elements)
    const unsigned short* aSrc = A + (size_t)(m0 + rowi) * K + csw;
    const unsigned short* bSrc = Bt + (size_t)(n0 + rowi) * K + csw;
    const int dstOff = (w * 8) * 64;                     // wave-uniform LDS base (elements)

    f32x4 acc[2][2];
    {
        f32x4 z = {0.f, 0.f, 0.f, 0.f};
        #pragma unroll
        for (int i = 0; i < 2; i++)
            #pragma unroll
            for (int j = 0; j < 2; j++) acc[i][j] = z;
    }

    const int wm = (w & 1) * 32;
    const int wn = (w >> 1) * 32;

    for (int kt = 0; kt < K; kt += 64) {
        __syncthreads();
        #pragma unroll
        for (int p = 0; p < 2; p++) {
            __builtin_amdgcn_global_load_lds(
                (gconst_void*)(aSrc + (size_t)p * 32 * K + kt),
                (lds_void*)(&lA[dstOff + p * 32 * 64]), 16, 0, 0);
            __builtin_amdgcn_global_load_lds(
                (gconst_void*)(bSrc + (size_t)p * 32 * K + kt),
                (lds_void*)(&lB[dstOff + p * 32 * 64]), 16, 0, 0);
        }
        __syncthreads();

        #pragma unroll
        for (int kk = 0; kk < 2; kk++) {
            bf16x8 af[2], bfr[2];
            const int xsw = ((kk * 4 + quad) ^ (l16 & 7)) * 8;
            #pragma unroll
            for (int t = 0; t < 2; t++) {
                af[t]  = *(const bf16x8*)&lA[(wm + t * 16 + l16) * 64 + xsw];
                bfr[t] = *(const bf16x8*)&lB[(wn + t * 16 + l16) * 64 + xsw];
            }
            #pragma unroll
            for (int i = 0; i < 2; i++)
                #pragma unroll
                for (int j = 0; j < 2; j++)
                    acc[i][j] = __builtin_amdgcn_mfma_f32_16x16x32_bf16(af[i], bfr[j], acc[i][j], 0, 0, 0);
        }
    }

    // epilogue: C/D layout col=lane&15, row=quad*4+reg  [m89]
    if (n0 < 2 * DMODEL) {
        #pragma unroll
        for (int j = 0; j < 2; j++) {
            const int n = n0 + wn + j * 16 + l16;
            const float bv = bias[n];
            const float scl = (n < DMODEL) ? 0.125f : 1.0f;
            #pragma unroll
            for (int i = 0; i < 2; i++) {
                const int mrow = m0 + wm + i * 16 + quad * 4;
                #pragma unroll
                for (int r = 0; r < 4; r++) {
                    float v = (acc[i][j][r] + bv) * scl;
                    qk[(size_t)(mrow + r) * 2048 + n] = f2bf(v);
                }
            }
        }
    } else {
        // v-block: transpose 64(m) x 64(n) tile through LDS (8 KB, staging space free).
        __syncthreads();   // all waves done with lA/lB fragment reads
        unsigned short* T = lds;   // [64 nl][64 ml], 16B chunks XOR-swizzled by nl&7
        #pragma unroll
        for (int j = 0; j < 2; j++) {
            const int nl = wn + j * 16 + l16;             // 0..63
            const float bv = bias[n0 + nl];
            #pragma unroll
            for (int i = 0; i < 2; i++) {
                const int ml0 = wm + i * 16 + quad * 4;   // 0..63, 4 consecutive m rows
                ushort4 pk;
                pk.x = f2bf(acc[i][j][0] + bv);
                pk.y = f2bf(acc[i][j][1] + bv);
                pk.z = f2bf(acc[i][j][2] + bv);
                pk.w = f2bf(acc[i][j][3] + bv);
                const int addr = nl * 64 + (((ml0 >> 3) ^ (nl & 7)) << 3) + (ml0 & 7);
                *(ushort4*)&T[addr] = pk;
            }
        }
        __syncthreads();
        // coalesced write-out: 64 d-rows x 64 s; 8 lanes x 16B cover one row
        const int b   = m0 >> 11;           // batch
        const int sg  = m0 & (S_LEN - 1);   // s offset within batch
        const int hd0 = n0 - 2 * DMODEL;
        const int c   = tid & 7;            // s-chunk 0..7
        #pragma unroll
        for (int pass = 0; pass < 2; pass++) {
            const int dl = (tid >> 3) + pass * 32;        // 0..63
            bf16x8 val = *(const bf16x8*)&T[dl * 64 + ((c ^ (dl & 7)) << 3)];
            *(bf16x8*)&vT[(size_t)(b * DMODEL + hd0 + dl) * S_LEN + sg + c * 8] = val;
        }
    }
}

// ---------------- GEMM2: out projection, 64x64 tile (4 blocks/CU at N=1024) --------
__global__ __launch_bounds__(256) void gemm_out(const unsigned short* __restrict__ A,
                                                const unsigned short* __restrict__ Bt,
                                                const float* __restrict__ bias,
                                                float* __restrict__ out,
                                                int M, int N, int K) {
    __shared__ unsigned short lA[64 * 64] __attribute__((aligned(16)));
    __shared__ unsigned short lB[64 * 64] __attribute__((aligned(16)));

    const int tid  = threadIdx.x;
    const int lane = tid & 63;
    const int w    = tid >> 6;
    const int quad = lane >> 4;
    const int l16  = lane & 15;

    const int m0 = blockIdx.x * 64;
    const int n0 = blockIdx.y * 64;

    const int rowi = tid >> 3;
    const int csw  = ((tid & 7) ^ (rowi & 7)) * 8;
    const unsigned short* aSrc = A + (size_t)(m0 + rowi) * K + csw;
    const unsigned short* bSrc = Bt + (size_t)(n0 + rowi) * K + csw;
    const int dstOff = (w * 8) * 64;   // wave-uniform LDS base (elements)

    f32x4 acc[2][2];
    {
        f32x4 z = {0.f, 0.f, 0.f, 0.f};
        #pragma unroll
        for (int i = 0; i < 2; i++)
            #pragma unroll
            for (int j = 0; j < 2; j++) acc[i][j] = z;
    }

    const int wm = (w & 1) * 32;
    const int wn = (w >> 1) * 32;

    for (int kt = 0; kt < K; kt += 64) {
        __syncthreads();
        #pragma unroll
        for (int p = 0; p < 2; p++) {
            __builtin_amdgcn_global_load_lds(
                (gconst_void*)(aSrc + (size_t)p * 32 * K + kt),
                (lds_void*)(&lA[dstOff + p * 32 * 64]), 16, 0, 0);
            __builtin_amdgcn_global_load_lds(
                (gconst_void*)(bSrc + (size_t)p * 32 * K + kt),
                (lds_void*)(&lB[dstOff + p * 32 * 64]), 16, 0, 0);
        }
        __syncthreads();

        #pragma unroll
        for (int kk = 0; kk < 2; kk++) {
            bf16x8 af[2], bfr[2];
            const int xsw = ((kk * 4 + quad) ^ (l16 & 7)) * 8;
            #pragma unroll
            for (int t = 0; t < 2; t++) {
                af[t]  = *(const bf16x8*)&lA[(wm + t * 16 + l16) * 64 + xsw];
                bfr[t] = *(const bf16x8*)&lB[(wn + t * 16 + l16) * 64 + xsw];
            }
            #pragma unroll
            for (int i = 0; i < 2; i++)
                #pragma unroll
                for (int j = 0; j < 2; j++)
                    acc[i][j] = __builtin_amdgcn_mfma_f32_16x16x32_bf16(af[i], bfr[j], acc[i][j], 0, 0, 0);
        }
    }

    #pragma unroll
    for (int j = 0; j < 2; j++) {
        const int n = n0 + wn + j * 16 + l16;
        const float bv = bias[n];
        #pragma unroll
        for (int i = 0; i < 2; i++) {
            const int mrow = m0 + wm + i * 16 + quad * 4;
            #pragma unroll
            for (int r = 0; r < 4; r++)
                out[(size_t)(mrow + r) * N + n] = acc[i][j][r] + bv;
        }
    }
}

// ---------------- windowed flash attention, double-buffered 64-key chunks ----------
__global__ __launch_bounds__(256) void attn_win(const unsigned short* __restrict__ qk, // [B*S, 2D] bf16
                                                const unsigned short* __restrict__ vT, // [B*D][S] bf16
                                                unsigned short* __restrict__ attnout,  // [B*S, D] bf16
                                                const int* __restrict__ wptr) {
    __shared__ unsigned short lK[2][64 * 64] __attribute__((aligned(16)));   // [key][d] swizzled
    __shared__ unsigned short lV[2][64 * 64] __attribute__((aligned(16)));   // [d][s]  swizzled
    __shared__ unsigned short lP[4][16 * 64] __attribute__((aligned(16)));   // per-wave P, swizzled

    const int W = wptr[0];
    const int tid  = threadIdx.x;
    const int lane = tid & 63;
    const int w    = tid >> 6;
    const int quad = lane >> 4;
    const int l16  = lane & 15;

    const int q0 = blockIdx.x * 64;
    const int h  = blockIdx.y;
    const size_t rowbase = (size_t)blockIdx.z * S_LEN;

    // Q fragments (A-layout: m=lane&15, k=quad*8+j) — q pre-scaled by 0.125 in GEMM1
    const int qrow = q0 + w * 16 + l16;
    bf16x8 qf0, qf1;
    {
        const unsigned short* qp = qk + (rowbase + qrow) * (2 * DMODEL) + h * HDIM;
        qf0 = *(const bf16x8*)(qp + quad * 8);
        qf1 = *(const bf16x8*)(qp + 32 + quad * 8);
    }

    const unsigned short* kbasep = qk + rowbase * (2 * DMODEL) + DMODEL + h * HDIM;
    const unsigned short* vbase  = vT + (size_t)(blockIdx.z * DMODEL + h * HDIM) * S_LEN;

    f32x4 o[4];
    { f32x4 z = {0.f,0.f,0.f,0.f}; o[0]=z; o[1]=z; o[2]=z; o[3]=z; }
    float lsum[4] = {0.f, 0.f, 0.f, 0.f};

    const int iq = q0 + w * 16 + quad * 4;
    int lo[4], hi[4];
    #pragma unroll
    for (int r = 0; r < 4; r++) {
        const int i = iq + r;
        lo[r] = max(i - W, 0);
        hi[r] = min(i + W, S_LEN - 1);
    }

    const int kbase = q0 - W;
    const int nch = (2 * W + 64 + 63) >> 6;
    // block-uniform chunk range: keep c iff [kc0, kc0+63] intersects [0, S_LEN)
    const int c_start = (kbase < 0) ? ((-kbase) >> 6) : 0;
    const int c_end   = min(nch, ((S_LEN - 1 - kbase) >> 6) + 1);

    const int skey = tid >> 3;   // staging row-within-pass 0..31
    const int sch  = tid & 7;    // staging dest chunk 0..7

    auto stage = [&](int buf, int kc0) {
        #pragma unroll
        for (int p = 0; p < 2; p++) {
            const int row = p * 32 + skey;                 // tile row (key for K, d for V)
            const int cs  = sch ^ (row & 7);               // swizzled source chunk
            int kg = kc0 + row;
            kg = kg < 0 ? 0 : (kg > S_LEN - 1 ? S_LEN - 1 : kg);
            __builtin_amdgcn_global_load_lds(
                (gconst_void*)(kbasep + (size_t)kg * (2 * DMODEL) + cs * 8),
                (lds_void*)(&lK[buf][w * 512 + p * 2048]), 16, 0, 0);
            int s0a = kc0 + cs * 8;
            s0a = s0a < 0 ? 0 : (s0a > S_LEN - 8 ? S_LEN - 8 : s0a);
            __builtin_amdgcn_global_load_lds(
                (gconst_void*)(vbase + (size_t)row * S_LEN + s0a),
                (lds_void*)(&lV[buf][w * 512 + p * 2048]), 16, 0, 0);
        }
    };

    stage(c_start & 1, kbase + c_start * 64);

    for (int c = c_start; c < c_end; c++) {
        const int kc0 = kbase + c * 64;
        const int buf = c & 1;

        __syncthreads();   // implicit vmcnt(0): buf's loads complete; all waves past buf^1 reads
        if (c + 1 < c_end) stage(buf ^ 1, kc0 + 64);

        // ---- S = Q K^T : 4 key-tiles x 2 k-steps
        f32x4 s4[4];
        { f32x4 z = {0.f,0.f,0.f,0.f}; s4[0]=z; s4[1]=z; s4[2]=z; s4[3]=z; }
        #pragma unroll
        for (int half = 0; half < 2; half++) {
            const bf16x8 qf = half ? qf1 : qf0;
            const int cs = half * 4 + quad;
            #pragma unroll
            for (int kt = 0; kt < 4; kt++) {
                const int key = kt * 16 + l16;
                bf16x8 kf = *(const bf16x8*)&lK[buf][key * 64 + ((cs ^ (key & 7)) << 3)];
                s4[kt] = __builtin_amdgcn_mfma_f32_16x16x32_bf16(qf, kf, s4[kt], 0, 0, 0);
            }
        }

        // ---- P = exp(S) (+ mask only on edge chunks); write P to per-wave LDS
        const bool fullvalid = (kc0 >= 0) && (kc0 + 63 < S_LEN) &&
                               (kc0 >= q0 + 63 - W) && (kc0 + 63 <= q0 + W);
        #pragma unroll
        for (int r = 0; r < 4; r++) {
            const int q = quad * 4 + r;
            const int qsw = q & 7;
            float ps = 0.f;
            #pragma unroll
            for (int kt = 0; kt < 4; kt++) {
                float p;
                if (fullvalid) {
                    p = __expf(s4[kt][r]);
                } else {
                    const int j = kc0 + kt * 16 + l16;
                    const bool v = (j >= lo[r]) && (j <= hi[r]);
                    p = v ? __expf(s4[kt][r]) : 0.f;
                }
                ps += p;
                const int ct = kt * 2 + (l16 >> 3);        // true key chunk
                lP[w][q * 64 + ((ct ^ qsw) << 3) + (l16 & 7)] = f2bf(p);
            }
            lsum[r] += ps;
        }

        __builtin_amdgcn_s_waitcnt(0xc07f);  // lgkmcnt(0): wave-local LDS RAW

        // ---- O += P V
        #pragma unroll
        for (int ks = 0; ks < 2; ks++) {
            const int cs = ks * 4 + quad;
            bf16x8 pf = *(const bf16x8*)&lP[w][l16 * 64 + ((cs ^ (l16 & 7)) << 3)];
            #pragma unroll
            for (int dt = 0; dt < 4; dt++) {
                const int d = dt * 16 + l16;
                bf16x8 vf = *(const bf16x8*)&lV[buf][d * 64 + ((cs ^ (d & 7)) << 3)];
                o[dt] = __builtin_amdgcn_mfma_f32_16x16x32_bf16(pf, vf, o[dt], 0, 0, 0);
            }
        }
    }

    // ---- normalize (one shuffle-reduce per row) + store bf16
    #pragma unroll
    for (int r = 0; r < 4; r++) {
        float l = lsum[r];
        l += __shfl_xor(l, 1);
        l += __shfl_xor(l, 2);
        l += __shfl_xor(l, 4);
        l += __shfl_xor(l, 8);
        const float inv = 1.f / l;
        #pragma unroll
        for (int t = 0; t < 4; t++) {
            attnout[(rowbase + iq + r) * DMODEL + h * HDIM + t * 16 + l16] = f2bf(o[t][r] * inv);
        }
    }
}

// ---------------- launch ----------------
extern "C" void kernel_launch(void* const* d_in, const int* in_sizes, int n_in,
                              void* d_out, int out_size, void* d_ws, size_t ws_size,
                              hipStream_t stream) {
    const float* x   = (const float*)d_in[0];  // [2,2048,1024]
    const float* w1  = (const float*)d_in[1];  // [3072,1024]
    const float* b1  = (const float*)d_in[2];  // [3072]
    const float* w2  = (const float*)d_in[3];  // [1024,1024]
    const float* b2  = (const float*)d_in[4];  // [1024]
    const int* wsz   = (const int*)d_in[5];    // window_size

    // workspace layout (40 MB total):
    //   [0,8M)   xb (x bf16)  -- reused as attnb after GEMM1 consumes it
    //   [8M,14M) w1b
    //   [14M,16M) w2b
    //   [16M,32M) qk  [4096][2048] bf16 (q scaled | k)
    //   [32M,40M) vT  [2048][2048] bf16 (per-head transposed v)
    char* ws = (char*)d_ws;
    unsigned short* xb    = (unsigned short*)(ws);
    unsigned short* attnb = (unsigned short*)(ws);
    unsigned short* w1b   = (unsigned short*)(ws + (8u << 20));
    unsigned short* w2b   = (unsigned short*)(ws + (14u << 20));
    unsigned short* qkb   = (unsigned short*)(ws + (16u << 20));
    unsigned short* vTb   = (unsigned short*)(ws + (32u << 20));

    const int M = 2 * S_LEN;  // 4096

    cvt_all<<<(N4_X + N4_W1 + N4_W2 + 255) / 256, 256, 0, stream>>>(x, w1, w2, xb, w1b, w2b);

    gemm_qkv<<<dim3(M / 64, 3 * DMODEL / 64), 256, 0, stream>>>(xb, w1b, b1, qkb, vTb, M, 3 * DMODEL, DMODEL);

    attn_win<<<dim3(S_LEN / 64, NHEAD, 2), 256, 0, stream>>>(qkb, vTb, attnb, wsz);

    gemm_out<<<dim3(M / 64, DMODEL / 64), 256, 0, stream>>>(attnb, w2b, b2, (float*)d_out, M, DMODEL, DMODEL);
}

// Round 9
// 155.821 us; speedup vs baseline: 1.0202x; 1.0202x over previous
//
#include <hip/hip_runtime.h>

// Problem constants (B=2, S=2048, D=1024, H=16, HD=64, W=128 from reference)
#define S_LEN 2048
#define DMODEL 1024
#define NHEAD 16
#define HDIM 64

typedef __bf16 bf16x8 __attribute__((ext_vector_type(8)));
typedef float f32x4 __attribute__((ext_vector_type(4)));

typedef __attribute__((address_space(1))) const void gconst_void;
typedef __attribute__((address_space(3))) void lds_void;

__device__ __forceinline__ unsigned short f2bf(float f) {
    unsigned u = __builtin_bit_cast(unsigned, f);
    u += 0x7fffu + ((u >> 16) & 1u);   // RNE
    return (unsigned short)(u >> 16);
}

// ---------------- fused fp32 -> bf16 convert (x, w1, w2 in one launch) ----------------
#define N4_X  (2 * S_LEN * DMODEL / 4)            // 1048576
#define N4_W1 (3 * DMODEL * DMODEL / 4)           // 786432
#define N4_W2 (DMODEL * DMODEL / 4)               // 262144
__global__ __launch_bounds__(256) void cvt_all(const float* __restrict__ x,
                                               const float* __restrict__ w1,
                                               const float* __restrict__ w2,
                                               unsigned short* __restrict__ xb,
                                               unsigned short* __restrict__ w1b,
                                               unsigned short* __restrict__ w2b) {
    int i = blockIdx.x * 256 + threadIdx.x;
    const float* s;
    unsigned short* d;
    int off;
    if (i < N4_X)            { s = x;  d = xb;  off = i; }
    else if (i < N4_X + N4_W1) { s = w1; d = w1b; off = i - N4_X; }
    else if (i < N4_X + N4_W1 + N4_W2) { s = w2; d = w2b; off = i - N4_X - N4_W1; }
    else return;
    float4 f = ((const float4*)s)[off];
    ushort4 o;
    o.x = f2bf(f.x); o.y = f2bf(f.y); o.z = f2bf(f.z); o.w = f2bf(f.w);
    ((ushort4*)d)[off] = o;
}

// ---------------- GEMM1: qkv projection, 64x128 tile (6 blocks/CU — empirical optimum)
// r8 showed 64x64 @8blk/CU REGRESSES (43.6us vs 37): past ~6 blk/CU the kernel is
// density-bound, not latency-bound. 64x128 is the sweet spot of this tile family.
// __launch_bounds__(256,6): cap VGPR ~85 so all 6 LDS-allowed blocks are admissible.
// n<1024  (q): scaled 0.125 -> qk[m*2048+n]       (bf16)
// n<2048  (k):              -> qk[m*2048+n]       (bf16)
// n>=2048 (v): LDS-transposed -> vT[(b*1024+hd)*2048 + s]  (bf16, coalesced)
__global__ __launch_bounds__(256, 6) void gemm_qkv(const unsigned short* __restrict__ A,
                                                   const unsigned short* __restrict__ Bt,
                                                   const float* __restrict__ bias,
                                                   unsigned short* __restrict__ qk,
                                                   unsigned short* __restrict__ vT,
                                                   int M, int N, int K) {
    __shared__ unsigned short lds[(64 + 128) * 64] __attribute__((aligned(16)));  // 24 KB
    unsigned short* lA = lds;                // 64 x 64
    unsigned short* lB = lds + 64 * 64;      // 128 x 64

    const int tid  = threadIdx.x;
    const int lane = tid & 63;
    const int w    = tid >> 6;
    const int quad = lane >> 4;
    const int l16  = lane & 15;

    const int m0 = blockIdx.x * 64;
    const int n0 = blockIdx.y * 128;

    const int rowi = tid >> 3;                           // 0..31
    const int csw  = ((tid & 7) ^ (rowi & 7)) * 8;       // swizzled source chunk (elements)
    const unsigned short* aSrc = A + (size_t)(m0 + rowi) * K + csw;
    const unsigned short* bSrc = Bt + (size_t)(n0 + rowi) * K + csw;
    const int dstOff = (w * 8) * 64;                     // wave-uniform LDS base (elements)

    f32x4 acc[2][4];
    {
        f32x4 z = {0.f, 0.f, 0.f, 0.f};
        #pragma unroll
        for (int i = 0; i < 2; i++)
            #pragma unroll
            for (int j = 0; j < 4; j++) acc[i][j] = z;
    }

    const int wm = (w & 1) * 32;
    const int wn = (w >> 1) * 64;

    for (int kt = 0; kt < K; kt += 64) {
        __syncthreads();
        #pragma unroll
        for (int p = 0; p < 2; p++) {
            __builtin_amdgcn_global_load_lds(
                (gconst_void*)(aSrc + (size_t)p * 32 * K + kt),
                (lds_void*)(&lA[dstOff + p * 32 * 64]), 16, 0, 0);
        }
        #pragma unroll
        for (int p = 0; p < 4; p++) {
            __builtin_amdgcn_global_load_lds(
                (gconst_void*)(bSrc + (size_t)p * 32 * K + kt),
                (lds_void*)(&lB[dstOff + p * 32 * 64]), 16, 0, 0);
        }
        __syncthreads();

        #pragma unroll
        for (int kk = 0; kk < 2; kk++) {
            bf16x8 af[2], bfr[4];
            const int xsw = ((kk * 4 + quad) ^ (l16 & 7)) * 8;
            #pragma unroll
            for (int t = 0; t < 2; t++)
                af[t] = *(const bf16x8*)&lA[(wm + t * 16 + l16) * 64 + xsw];
            #pragma unroll
            for (int t = 0; t < 4; t++)
                bfr[t] = *(const bf16x8*)&lB[(wn + t * 16 + l16) * 64 + xsw];
            #pragma unroll
            for (int i = 0; i < 2; i++)
                #pragma unroll
                for (int j = 0; j < 4; j++)
                    acc[i][j] = __builtin_amdgcn_mfma_f32_16x16x32_bf16(af[i], bfr[j], acc[i][j], 0, 0, 0);
        }
    }

    // epilogue: C/D layout col=lane&15, row=quad*4+reg  [m89]
    if (n0 < 2 * DMODEL) {
        #pragma unroll
        for (int j = 0; j < 4; j++) {
            const int n = n0 + wn + j * 16 + l16;
            const float bv = bias[n];
            const float scl = (n < DMODEL) ? 0.125f : 1.0f;
            #pragma unroll
            for (int i = 0; i < 2; i++) {
                const int mrow = m0 + wm + i * 16 + quad * 4;
                #pragma unroll
                for (int r = 0; r < 4; r++) {
                    float v = (acc[i][j][r] + bv) * scl;
                    qk[(size_t)(mrow + r) * 2048 + n] = f2bf(v);
                }
            }
        }
    } else {
        // v-block: transpose 64(m) x 128(n) tile through LDS (16 KB fits in staging space).
        __syncthreads();   // all waves done with lA/lB fragment reads
        unsigned short* T = lds;   // [128 nl][64 ml], 16B chunks XOR-swizzled by nl&7
        #pragma unroll
        for (int j = 0; j < 4; j++) {
            const int nl = wn + j * 16 + l16;             // 0..127
            const float bv = bias[n0 + nl];
            #pragma unroll
            for (int i = 0; i < 2; i++) {
                const int ml0 = wm + i * 16 + quad * 4;   // 0..63, 4 consecutive m rows
                ushort4 pk;
                pk.x = f2bf(acc[i][j][0] + bv);
                pk.y = f2bf(acc[i][j][1] + bv);
                pk.z = f2bf(acc[i][j][2] + bv);
                pk.w = f2bf(acc[i][j][3] + bv);
                const int addr = nl * 64 + (((ml0 >> 3) ^ (nl & 7)) << 3) + (ml0 & 7);
                *(ushort4*)&T[addr] = pk;
            }
        }
        __syncthreads();
        // coalesced write-out: 128 d-rows x 64 s; 8 lanes x 16B cover one row
        const int b   = m0 >> 11;           // batch
        const int sg  = m0 & (S_LEN - 1);   // s offset within batch
        const int hd0 = n0 - 2 * DMODEL;
        const int c   = tid & 7;            // s-chunk 0..7
        #pragma unroll
        for (int pass = 0; pass < 4; pass++) {
            const int dl = (tid >> 3) + pass * 32;        // 0..127
            bf16x8 val = *(const bf16x8*)&T[dl * 64 + ((c ^ (dl & 7)) << 3)];
            *(bf16x8*)&vT[(size_t)(b * DMODEL + hd0 + dl) * S_LEN + sg + c * 8] = val;
        }
    }
}

// ---------------- GEMM2: out projection, 64x64 tile (4 blocks/CU at N=1024) --------
__global__ __launch_bounds__(256) void gemm_out(const unsigned short* __restrict__ A,
                                                const unsigned short* __restrict__ Bt,
                                                const float* __restrict__ bias,
                                                float* __restrict__ out,
                                                int M, int N, int K) {
    __shared__ unsigned short lA[64 * 64] __attribute__((aligned(16)));
    __shared__ unsigned short lB[64 * 64] __attribute__((aligned(16)));

    const int tid  = threadIdx.x;
    const int lane = tid & 63;
    const int w    = tid >> 6;
    const int quad = lane >> 4;
    const int l16  = lane & 15;

    const int m0 = blockIdx.x * 64;
    const int n0 = blockIdx.y * 64;

    const int rowi = tid >> 3;
    const int csw  = ((tid & 7) ^ (rowi & 7)) * 8;
    const unsigned short* aSrc = A + (size_t)(m0 + rowi) * K + csw;
    const unsigned short* bSrc = Bt + (size_t)(n0 + rowi) * K + csw;
    const int dstOff = (w * 8) * 64;   // wave-uniform LDS base (elements)

    f32x4 acc[2][2];
    {
        f32x4 z = {0.f, 0.f, 0.f, 0.f};
        #pragma unroll
        for (int i = 0; i < 2; i++)
            #pragma unroll
            for (int j = 0; j < 2; j++) acc[i][j] = z;
    }

    const int wm = (w & 1) * 32;
    const int wn = (w >> 1) * 32;

    for (int kt = 0; kt < K; kt += 64) {
        __syncthreads();
        #pragma unroll
        for (int p = 0; p < 2; p++) {
            __builtin_amdgcn_global_load_lds(
                (gconst_void*)(aSrc + (size_t)p * 32 * K + kt),
                (lds_void*)(&lA[dstOff + p * 32 * 64]), 16, 0, 0);
            __builtin_amdgcn_global_load_lds(
                (gconst_void*)(bSrc + (size_t)p * 32 * K + kt),
                (lds_void*)(&lB[dstOff + p * 32 * 64]), 16, 0, 0);
        }
        __syncthreads();

        #pragma unroll
        for (int kk = 0; kk < 2; kk++) {
            bf16x8 af[2], bfr[2];
            const int xsw = ((kk * 4 + quad) ^ (l16 & 7)) * 8;
            #pragma unroll
            for (int t = 0; t < 2; t++) {
                af[t]  = *(const bf16x8*)&lA[(wm + t * 16 + l16) * 64 + xsw];
                bfr[t] = *(const bf16x8*)&lB[(wn + t * 16 + l16) * 64 + xsw];
            }
            #pragma unroll
            for (int i = 0; i < 2; i++)
                #pragma unroll
                for (int j = 0; j < 2; j++)
                    acc[i][j] = __builtin_amdgcn_mfma_f32_16x16x32_bf16(af[i], bfr[j], acc[i][j], 0, 0, 0);
        }
    }

    #pragma unroll
    for (int j = 0; j < 2; j++) {
        const int n = n0 + wn + j * 16 + l16;
        const float bv = bias[n];
        #pragma unroll
        for (int i = 0; i < 2; i++) {
            const int mrow = m0 + wm + i * 16 + quad * 4;
            #pragma unroll
            for (int r = 0; r < 4; r++)
                out[(size_t)(mrow + r) * N + n] = acc[i][j][r] + bv;
        }
    }
}

// ---------------- windowed flash attention, double-buffered 64-key chunks ----------
__global__ __launch_bounds__(256) void attn_win(const unsigned short* __restrict__ qk, // [B*S, 2D] bf16
                                                const unsigned short* __restrict__ vT, // [B*D][S] bf16
                                                unsigned short* __restrict__ attnout,  // [B*S, D] bf16
                                                const int* __restrict__ wptr) {
    __shared__ unsigned short lK[2][64 * 64] __attribute__((aligned(16)));   // [key][d] swizzled
    __shared__ unsigned short lV[2][64 * 64] __attribute__((aligned(16)));   // [d][s]  swizzled
    __shared__ unsigned short lP[4][16 * 64] __attribute__((aligned(16)));   // per-wave P, swizzled

    const int W = wptr[0];
    const int tid  = threadIdx.x;
    const int lane = tid & 63;
    const int w    = tid >> 6;
    const int quad = lane >> 4;
    const int l16  = lane & 15;

    const int q0 = blockIdx.x * 64;
    const int h  = blockIdx.y;
    const size_t rowbase = (size_t)blockIdx.z * S_LEN;

    // Q fragments (A-layout: m=lane&15, k=quad*8+j) — q pre-scaled by 0.125 in GEMM1
    const int qrow = q0 + w * 16 + l16;
    bf16x8 qf0, qf1;
    {
        const unsigned short* qp = qk + (rowbase + qrow) * (2 * DMODEL) + h * HDIM;
        qf0 = *(const bf16x8*)(qp + quad * 8);
        qf1 = *(const bf16x8*)(qp + 32 + quad * 8);
    }

    const unsigned short* kbasep = qk + rowbase * (2 * DMODEL) + DMODEL + h * HDIM;
    const unsigned short* vbase  = vT + (size_t)(blockIdx.z * DMODEL + h * HDIM) * S_LEN;

    f32x4 o[4];
    { f32x4 z = {0.f,0.f,0.f,0.f}; o[0]=z; o[1]=z; o[2]=z; o[3]=z; }
    float lsum[4] = {0.f, 0.f, 0.f, 0.f};

    const int iq = q0 + w * 16 + quad * 4;
    int lo[4], hi[4];
    #pragma unroll
    for (int r = 0; r < 4; r++) {
        const int i = iq + r;
        lo[r] = max(i - W, 0);
        hi[r] = min(i + W, S_LEN - 1);
    }

    const int kbase = q0 - W;
    const int nch = (2 * W + 64 + 63) >> 6;
    // block-uniform chunk range: keep c iff [kc0, kc0+63] intersects [0, S_LEN)
    const int c_start = (kbase < 0) ? ((-kbase) >> 6) : 0;
    const int c_end   = min(nch, ((S_LEN - 1 - kbase) >> 6) + 1);

    const int skey = tid >> 3;   // staging row-within-pass 0..31
    const int sch  = tid & 7;    // staging dest chunk 0..7

    auto stage = [&](int buf, int kc0) {
        #pragma unroll
        for (int p = 0; p < 2; p++) {
            const int row = p * 32 + skey;                 // tile row (key for K, d for V)
            const int cs  = sch ^ (row & 7);               // swizzled source chunk
            int kg = kc0 + row;
            kg = kg < 0 ? 0 : (kg > S_LEN - 1 ? S_LEN - 1 : kg);
            __builtin_amdgcn_global_load_lds(
                (gconst_void*)(kbasep + (size_t)kg * (2 * DMODEL) + cs * 8),
                (lds_void*)(&lK[buf][w * 512 + p * 2048]), 16, 0, 0);
            int s0a = kc0 + cs * 8;
            s0a = s0a < 0 ? 0 : (s0a > S_LEN - 8 ? S_LEN - 8 : s0a);
            __builtin_amdgcn_global_load_lds(
                (gconst_void*)(vbase + (size_t)row * S_LEN + s0a),
                (lds_void*)(&lV[buf][w * 512 + p * 2048]), 16, 0, 0);
        }
    };

    stage(c_start & 1, kbase + c_start * 64);

    for (int c = c_start; c < c_end; c++) {
        const int kc0 = kbase + c * 64;
        const int buf = c & 1;

        __syncthreads();   // implicit vmcnt(0): buf's loads complete; all waves past buf^1 reads
        if (c + 1 < c_end) stage(buf ^ 1, kc0 + 64);

        // ---- S = Q K^T : 4 key-tiles x 2 k-steps
        f32x4 s4[4];
        { f32x4 z = {0.f,0.f,0.f,0.f}; s4[0]=z; s4[1]=z; s4[2]=z; s4[3]=z; }
        #pragma unroll
        for (int half = 0; half < 2; half++) {
            const bf16x8 qf = half ? qf1 : qf0;
            const int cs = half * 4 + quad;
            #pragma unroll
            for (int kt = 0; kt < 4; kt++) {
                const int key = kt * 16 + l16;
                bf16x8 kf = *(const bf16x8*)&lK[buf][key * 64 + ((cs ^ (key & 7)) << 3)];
                s4[kt] = __builtin_amdgcn_mfma_f32_16x16x32_bf16(qf, kf, s4[kt], 0, 0, 0);
            }
        }

        // ---- P = exp(S) (+ mask only on edge chunks); write P to per-wave LDS
        const bool fullvalid = (kc0 >= 0) && (kc0 + 63 < S_LEN) &&
                               (kc0 >= q0 + 63 - W) && (kc0 + 63 <= q0 + W);
        #pragma unroll
        for (int r = 0; r < 4; r++) {
            const int q = quad * 4 + r;
            const int qsw = q & 7;
            float ps = 0.f;
            #pragma unroll
            for (int kt = 0; kt < 4; kt++) {
                float p;
                if (fullvalid) {
                    p = __expf(s4[kt][r]);
                } else {
                    const int j = kc0 + kt * 16 + l16;
                    const bool v = (j >= lo[r]) && (j <= hi[r]);
                    p = v ? __expf(s4[kt][r]) : 0.f;
                }
                ps += p;
                const int ct = kt * 2 + (l16 >> 3);        // true key chunk
                lP[w][q * 64 + ((ct ^ qsw) << 3) + (l16 & 7)] = f2bf(p);
            }
            lsum[r] += ps;
        }

        __builtin_amdgcn_s_waitcnt(0xc07f);  // lgkmcnt(0): wave-local LDS RAW

        // ---- O += P V
        #pragma unroll
        for (int ks = 0; ks < 2; ks++) {
            const int cs = ks * 4 + quad;
            bf16x8 pf = *(const bf16x8*)&lP[w][l16 * 64 + ((cs ^ (l16 & 7)) << 3)];
            #pragma unroll
            for (int dt = 0; dt < 4; dt++) {
                const int d = dt * 16 + l16;
                bf16x8 vf = *(const bf16x8*)&lV[buf][d * 64 + ((cs ^ (d & 7)) << 3)];
                o[dt] = __builtin_amdgcn_mfma_f32_16x16x32_bf16(pf, vf, o[dt], 0, 0, 0);
            }
        }
    }

    // ---- normalize (one shuffle-reduce per row) + store bf16
    #pragma unroll
    for (int r = 0; r < 4; r++) {
        float l = lsum[r];
        l += __shfl_xor(l, 1);
        l += __shfl_xor(l, 2);
        l += __shfl_xor(l, 4);
        l += __shfl_xor(l, 8);
        const float inv = 1.f / l;
        #pragma unroll
        for (int t = 0; t < 4; t++) {
            attnout[(rowbase + iq + r) * DMODEL + h * HDIM + t * 16 + l16] = f2bf(o[t][r] * inv);
        }
    }
}

// ---------------- launch ----------------
extern "C" void kernel_launch(void* const* d_in, const int* in_sizes, int n_in,
                              void* d_out, int out_size, void* d_ws, size_t ws_size,
                              hipStream_t stream) {
    const float* x   = (const float*)d_in[0];  // [2,2048,1024]
    const float* w1  = (const float*)d_in[1];  // [3072,1024]
    const float* b1  = (const float*)d_in[2];  // [3072]
    const float* w2  = (const float*)d_in[3];  // [1024,1024]
    const float* b2  = (const float*)d_in[4];  // [1024]
    const int* wsz   = (const int*)d_in[5];    // window_size

    // workspace layout (40 MB total):
    //   [0,8M)   xb (x bf16)  -- reused as attnb after GEMM1 consumes it
    //   [8M,14M) w1b
    //   [14M,16M) w2b
    //   [16M,32M) qk  [4096][2048] bf16 (q scaled | k)
    //   [32M,40M) vT  [2048][2048] bf16 (per-head transposed v)
    char* ws = (char*)d_ws;
    unsigned short* xb    = (unsigned short*)(ws);
    unsigned short* attnb = (unsigned short*)(ws);
    unsigned short* w1b   = (unsigned short*)(ws + (8u << 20));
    unsigned short* w2b   = (unsigned short*)(ws + (14u << 20));
    unsigned short* qkb   = (unsigned short*)(ws + (16u << 20));
    unsigned short* vTb   = (unsigned short*)(ws + (32u << 20));

    const int M = 2 * S_LEN;  // 4096

    cvt_all<<<(N4_X + N4_W1 + N4_W2 + 255) / 256, 256, 0, stream>>>(x, w1, w2, xb, w1b, w2b);

    gemm_qkv<<<dim3(M / 64, 3 * DMODEL / 128), 256, 0, stream>>>(xb, w1b, b1, qkb, vTb, M, 3 * DMODEL, DMODEL);

    attn_win<<<dim3(S_LEN / 64, NHEAD, 2), 256, 0, stream>>>(qkb, vTb, attnb, wsz);

    gemm_out<<<dim3(M / 64, DMODEL / 64), 256, 0, stream>>>(attnb, w2b, b2, (float*)d_out, M, DMODEL, DMODEL);
}